// Round 5
// baseline (944.466 us; speedup 1.0000x reference)
//
#include <hip/hip_runtime.h>
#include <cmath>

typedef unsigned short u16;
using short8 = __attribute__((ext_vector_type(8))) short;   // 8 x bf16
using f32x4  = __attribute__((ext_vector_type(4))) float;   // MFMA acc

// ---------- helpers ----------
__device__ __forceinline__ u16 f2bf(float f) {  // fp32 -> bf16 RNE
  union { float f; unsigned u; } c; c.f = f;
  unsigned r = c.u + 0x7fffu + ((c.u >> 16) & 1u);
  return (u16)(r >> 16);
}
__device__ __forceinline__ float bf2f(u16 b) {
  union { unsigned u; float f; } c; c.u = ((unsigned)b) << 16;
  return c.f;
}

__device__ __forceinline__ void gld_lds16(void* lds, const void* g) {
  __builtin_amdgcn_global_load_lds(
      (const __attribute__((address_space(1))) void*)g,
      (__attribute__((address_space(3))) void*)lds, 16, 0, 0);
}

// fast GELU (tanh approx, max err ~1e-3 << bf16 threshold)
__device__ __forceinline__ float gelu_fast(float t) {
  float u = 0.7978845608f * t * (1.f + 0.044715f * t * t);
  float th = 1.f - 2.f / (__expf(2.f * u) + 1.f);
  return 0.5f * t * (1.f + th);
}

// ---------- fp32 -> bf16 convert ----------
__global__ __launch_bounds__(256) void cvt_bf16(const float* __restrict__ in,
                                                u16* __restrict__ out, int n4) {
  int i = blockIdx.x * 256 + threadIdx.x;
  if (i >= n4) return;
  float4 v = ((const float4*)in)[i];
  ushort4 o;
  o.x = f2bf(v.x); o.y = f2bf(v.y); o.z = f2bf(v.z); o.w = f2bf(v.w);
  ((ushort4*)out)[i] = o;
}

// fp32 -> bf16 into strided (padded) rows
__global__ __launch_bounds__(256) void cvt_pad(const float* __restrict__ in,
                                               u16* __restrict__ out,
                                               int incols4, int outstride, int n4) {
  int i = blockIdx.x * 256 + threadIdx.x;
  if (i >= n4) return;
  int row = i / incols4, c = i - row * incols4;
  float4 v = ((const float4*)in)[i];
  ushort4 o;
  o.x = f2bf(v.x); o.y = f2bf(v.y); o.z = f2bf(v.z); o.w = f2bf(v.w);
  *(ushort4*)&out[(size_t)row * outstride + c * 4] = o;
}

// ---------- relative-position bias table ----------
__global__ __launch_bounds__(256) void btab_kernel(const float* __restrict__ rel_embed,
                                                   float* __restrict__ btab) {
  int idx = blockIdx.x * 256 + threadIdx.x;
  if (idx >= 16 * 2048) return;
  int h = idx >> 11;
  int d = idx & 2047;
  if (d >= 2047) return;
  int rel = d - 1023;
  int bucket = (rel > 0) ? 160 : 0;
  int ar = rel < 0 ? -rel : rel;
  if (ar < 80) {
    bucket += ar;
  } else {
    int large = 80 + (int)(logf((float)ar / 80.0f) / 2.3025851f * 80.0f);
    if (large > 159) large = 159;
    bucket += large;
  }
  btab[h * 2048 + d] = rel_embed[bucket * 16 + h];
}

// ---------- gate ----------
__global__ __launch_bounds__(256) void gate_kernel(const float* __restrict__ x,
                                                   const float* __restrict__ Wg,
                                                   const float* __restrict__ bg,
                                                   const float* __restrict__ gc,
                                                   float* __restrict__ gate_out) {
  int gw = blockIdx.x * 4 + (threadIdx.x >> 6);
  int lane = threadIdx.x & 63;
  int s = gw & 1023, bh = gw >> 10, b = bh >> 4, h = bh & 15;
  float wA = Wg[lane] + Wg[64 + lane] + Wg[128 + lane] + Wg[192 + lane];
  float wB = Wg[256 + lane] + Wg[320 + lane] + Wg[384 + lane] + Wg[448 + lane];
  float xv = x[((size_t)(b * 1024 + s)) * 1024 + h * 64 + lane];
  float pa = xv * wA, pb = xv * wB;
  #pragma unroll
  for (int m = 1; m < 64; m <<= 1) {
    pa += __shfl_xor(pa, m, 64);
    pb += __shfl_xor(pb, m, 64);
  }
  if (lane == 0) {
    float bgA = bg[0] + bg[1] + bg[2] + bg[3];
    float bgB = bg[4] + bg[5] + bg[6] + bg[7];
    float ga = 1.f / (1.f + expf(-(pa + bgA)));
    float gb = 1.f / (1.f + expf(-(pb + bgB)));
    gate_out[(size_t)bh * 1024 + s] = ga * (gb * gc[h] - 1.f) + 2.f;
  }
}

// ---------- V transpose: vt[bh][d][s] ----------
__global__ __launch_bounds__(256) void vtrans_kernel(const u16* __restrict__ vb,
                                                     u16* __restrict__ vt) {
  __shared__ u16 tile[64 * 65];
  int bh = blockIdx.y, b = bh >> 4, h = bh & 15;
  int s0 = blockIdx.x * 64;
  int tid = threadIdx.x;
  int r = tid >> 3, c = (tid & 7) * 8;
  #pragma unroll
  for (int p = 0; p < 2; ++p) {
    int s = p * 32 + r;
    uint4 vv = *(const uint4*)&vb[((size_t)(b * 1024 + s0 + s)) * 1024 + h * 64 + c];
    const u16* pv = (const u16*)&vv;
    #pragma unroll
    for (int e = 0; e < 8; ++e) tile[(c + e) * 65 + s] = pv[e];
  }
  __syncthreads();
  int d = tid & 63, jc0 = tid >> 6;
  #pragma unroll
  for (int jc = jc0; jc < 8; jc += 4) {
    u16 tmp[8];
    #pragma unroll
    for (int e = 0; e < 8; ++e) tmp[e] = tile[d * 65 + jc * 8 + e];
    *(uint4*)&vt[((size_t)(bh * 64 + d)) * 1024 + s0 + jc * 8] = *(uint4*)tmp;
  }
}

// ---------- GEMM 256x256, BK=32, 8 waves, 2-phase double-buffer ----------
// BK=32 -> LDS 64KB -> 2 blocks/CU (512 slots chip-wide): every launch grid
// (272/256/192 blocks) is fully co-resident (no scheduling-round quantization,
// the R4 counter finding), and the co-resident block's MFMA covers this
// block's stage+vmcnt(0) drain. Per K-tile: issue next-tile stage (4 x
// global_load_lds/thread) -> ds_read/MFMA current tile -> vmcnt(0) -> barrier.
// LDS chunk-XOR swizzle; staging pre-swizzles the per-lane GLOBAL address,
// LDS dest stays linear (rule 21); reads apply the same XOR (0 conflicts,
// verified R1-R4).
// MODE 0: QKV epilogue (seg bias + q*0.125, bf16 x3)
// MODE 2: FF1 gelu (cols<4096, bias0) / adapter elu (cols>=4096, bias1)
// MODE 3: fp32 partials (split-K x4), 4M-float stride, P0|P1 contiguous,
//         kz=2 -> outf2, kz=3 -> outf3
#define VMCNT(n) asm volatile("s_waitcnt vmcnt(" #n ")" ::: "memory")

#define G256_LDA(BUF, MH)                                                   \
  af_[0] = *(const short8*)&lds[BUF][0][aBase + (MH) * 2048 + 0];           \
  af_[1] = *(const short8*)&lds[BUF][0][aBase + (MH) * 2048 + 512];         \
  af_[2] = *(const short8*)&lds[BUF][0][aBase + (MH) * 2048 + 1024];        \
  af_[3] = *(const short8*)&lds[BUF][0][aBase + (MH) * 2048 + 1536];
#define G256_LDB(BUF)                                                       \
  bf_[0] = *(const short8*)&lds[BUF][1][bBase + 0];                         \
  bf_[1] = *(const short8*)&lds[BUF][1][bBase + 512];                       \
  bf_[2] = *(const short8*)&lds[BUF][1][bBase + 1024];                      \
  bf_[3] = *(const short8*)&lds[BUF][1][bBase + 1536];
#define G256_MFMA(MH)                                                       \
  _Pragma("unroll") for (int mi = 0; mi < 4; ++mi)                          \
  _Pragma("unroll") for (int ni = 0; ni < 4; ++ni)                          \
    acc[(MH) * 4 + mi][ni] = __builtin_amdgcn_mfma_f32_16x16x32_bf16(       \
        af_[mi], bf_[ni], acc[(MH) * 4 + mi][ni], 0, 0, 0);
#define G256_TILE(BUF)                                                      \
  G256_LDB(BUF)                                                             \
  G256_LDA(BUF, 0)                                                          \
  G256_MFMA(0)                                                              \
  G256_LDA(BUF, 1)                                                          \
  G256_MFMA(1)

template <int MODE>
__global__ __launch_bounds__(512, 4) void gemm256(
    const u16* __restrict__ A, const u16* __restrict__ Bw,
    int lda, int ldb, int kt_hi, int kt_lo, int z_hi,
    const float* __restrict__ bias0, const float* __restrict__ bias1,
    const float* __restrict__ bias2,
    float* __restrict__ outf, float* __restrict__ outf2,
    float* __restrict__ outf3, int ldo,
    u16* __restrict__ ob0, u16* __restrict__ ob1, u16* __restrict__ ob2) {
  __shared__ __align__(16) u16 lds[2][2][8192];   // [buf][A/B][256 rows x 32 cols]

  const int tid = threadIdx.x;
  const int lane = tid & 63, wave = tid >> 6;
  const int quad = lane >> 4, l16 = lane & 15;
  const int wm = wave >> 2, wn = wave & 3;

  // XCD-aware bijective swizzle (all grids are multiples of 8 blocks)
  const int gx = gridDim.x, gy = gridDim.y;
  int flat = blockIdx.x + gx * (blockIdx.y + gy * blockIdx.z);
  const int cpx = (gx * gy * gridDim.z) >> 3;
  flat = (flat & 7) * cpx + (flat >> 3);
  const int bmi = flat % gx;
  int rest = flat / gx;
  const int bni = rest % gy;
  const int kz = rest / gy;

  const int bm = bmi * 256, bn = bni * 256;
  const int nkt = (kz < z_hi) ? kt_hi : kt_lo;   // K-tiles of 32; must be EVEN
  const int ktb = (kz < z_hi) ? kz * kt_hi : z_hi * kt_hi + (kz - z_hi) * kt_lo;

  // staging geometry: lane l stages row (wave*16 + l/4) (+128 for 2nd load),
  // global 16B chunk (l&3)^((row>>1)&3) -> linear LDS dest.
  const int srow = wave * 16 + (lane >> 2);
  const int sk = (((lane & 3) ^ ((lane >> 3) & 3)) << 3);
  const u16* aG = A + (size_t)(bm + srow) * lda + (size_t)ktb * 32 + sk;
  const u16* bG = Bw + (size_t)(bn + srow) * ldb + (size_t)ktb * 32 + sk;
  const size_t aS = (size_t)128 * lda, bS = (size_t)128 * ldb;

  // frag read bases (u16 index inside one [8192] region)
  const int xsw = ((quad ^ ((l16 >> 1) & 3)) << 3);
  const int aBase = (wm * 128 + l16) * 32 + xsw;
  const int bBase = (wn * 64 + l16) * 32 + xsw;

  auto stA = [&](int buf, int kt) {
    const u16* g = aG + kt * 32;
    u16* d = (u16*)&lds[buf][0][wave * 512];
    gld_lds16(d, g);
    gld_lds16(d + 4096, g + aS);
  };
  auto stB = [&](int buf, int kt) {
    const u16* g = bG + kt * 32;
    u16* d = (u16*)&lds[buf][1][wave * 512];
    gld_lds16(d, g);
    gld_lds16(d + 4096, g + bS);
  };

  f32x4 acc[8][4] = {};
  short8 af_[4], bf_[4];

  // prologue: stage tile 0 -> buf0, drain, barrier
  stA(0, 0); stB(0, 0);
  VMCNT(0);
  __builtin_amdgcn_s_barrier();

  for (int J = 0; J < (nkt >> 1); ++J) {
    {  // even tile t=2J in buf0; prefetch t+1 -> buf1 (always exists)
      const int t1 = 2 * J + 1;
      stA(1, t1); stB(1, t1);
      G256_TILE(0)
      VMCNT(0);
      __builtin_amdgcn_s_barrier();
    }
    {  // odd tile t=2J+1 in buf1; prefetch t+2 -> buf0 (if exists)
      const int t2 = 2 * J + 2;
      if (t2 < nkt) { stA(0, t2); stB(0, t2); }
      G256_TILE(1)
      VMCNT(0);
      __builtin_amdgcn_s_barrier();
    }
  }

  const int m0 = bm + wm * 128 + quad * 4;
  const int n0 = bn + wn * 64 + l16;

  if constexpr (MODE == 0) {
    const int seg = bn >> 10;  // tile never straddles a 1024 segment
    const float* bs = seg == 0 ? bias0 : (seg == 1 ? bias1 : bias2);
    u16* dst = seg == 0 ? ob0 : (seg == 1 ? ob1 : ob2);
    const float sc = seg == 0 ? 0.125f : 1.0f;
    const int nb = (bn & 1023) + wn * 64 + l16;
    #pragma unroll
    for (int a = 0; a < 8; ++a)
      #pragma unroll
      for (int ni = 0; ni < 4; ++ni) {
        int nn = nb + ni * 16;
        float bv = bs[nn];
        #pragma unroll
        for (int r = 0; r < 4; ++r) {
          int m = m0 + a * 16 + r;
          dst[(size_t)m * 1024 + nn] = f2bf((acc[a][ni][r] + bv) * sc);
        }
      }
  } else if constexpr (MODE == 2) {
    const bool is_gelu = (bn < 4096);   // block-uniform
    #pragma unroll
    for (int a = 0; a < 8; ++a)
      #pragma unroll
      for (int ni = 0; ni < 4; ++ni) {
        int nn = n0 + ni * 16;
        float bv = is_gelu ? bias0[nn] : bias1[nn - 4096];
        #pragma unroll
        for (int r = 0; r < 4; ++r) {
          int m = m0 + a * 16 + r;
          float t = acc[a][ni][r] + bv;
          float res;
          if (is_gelu) res = gelu_fast(t);
          else         res = t > 0.f ? t : (__expf(t) - 1.f);
          ob0[(size_t)m * 4352 + nn] = f2bf(res);
        }
      }
  } else {  // MODE 3: fp32 partials
    float* op = (kz == 0) ? outf
              : (kz == 1) ? outf + 4194304
              : (kz == 2) ? outf2 : outf3;
    #pragma unroll
    for (int a = 0; a < 8; ++a)
      #pragma unroll
      for (int ni = 0; ni < 4; ++ni) {
        int nn = n0 + ni * 16;
        #pragma unroll
        for (int r = 0; r < 4; ++r)
          op[(size_t)(m0 + a * 16 + r) * ldo + nn] = acc[a][ni][r];
      }
  }
}

// ---------- flash attention: LDS-staged K/V, double-buffered (2-phase) ----------
// R4-verified structure: global_load_lds for tile jt+1 issued BEFORE compute
// of tile jt, drains at end-of-iteration vmcnt(0)+barrier. Grid (bh, it0):
// flat%8 = bh%8 -> one XCD per (b,h) (FETCH 70->13MB, R3-verified).
__global__ __launch_bounds__(256) void attn_kernel(
    const u16* __restrict__ qb, const u16* __restrict__ kb, const u16* __restrict__ vt,
    const float* __restrict__ gate, const float* __restrict__ btab,
    u16* __restrict__ ctxb) {
  __shared__ __align__(16) u16 Ks[2][64 * 64];
  __shared__ __align__(16) u16 Vs[2][64 * 64];
  __shared__ __align__(16) u16 Ps[4][16 * 64];
  __shared__ u16 btl[2048];
  __shared__ float gbuf[64];

  const int tid = threadIdx.x;
  const int lane = tid & 63, wave = tid >> 6;
  const int quad = lane >> 4, l16 = lane & 15;
  const int bh = blockIdx.x, b = bh >> 4, h = bh & 15;
  const int it0 = blockIdx.y * 64;
  const int sr = lane & 15;
  const int skc = (lane >> 4) * 8;

  // stage K/V tile jt into buffer buf (4 x global_load_lds per wave-slab)
  auto stage = [&](int buf, int jt) {
    const int j0 = jt * 64;
    #pragma unroll
    for (int hf = 0; hf < 2; ++hf) {
      gld_lds16(&Ks[buf][wave * 1024 + hf * 512],
                &kb[((size_t)(b * 1024 + j0 + wave * 16 + sr)) * 1024 + h * 64 + hf * 32 + skc]);
      gld_lds16(&Vs[buf][wave * 1024 + hf * 512],
                &vt[((size_t)(bh * 64 + wave * 16 + sr)) * 1024 + j0 + hf * 32 + skc]);
    }
  };

  for (int idx = tid; idx < 2047; idx += 256) btl[idx] = f2bf(btab[h * 2048 + idx]);
  if (tid < 64) gbuf[tid] = gate[(size_t)bh * 1024 + it0 + tid];

  // Q fragments held in registers for the whole kernel
  short8 aq[2];
  #pragma unroll
  for (int c = 0; c < 2; ++c)
    aq[c] = *(const short8*)&qb[((size_t)(b * 1024 + it0 + wave * 16 + l16)) * 1024 +
                                h * 64 + c * 32 + quad * 8];

  f32x4 oacc[4] = {};
  float mrow[4], lrow[4];
  #pragma unroll
  for (int r = 0; r < 4; ++r) { mrow[r] = -1e30f; lrow[r] = 0.f; }

  stage(0, 0);
  __syncthreads();   // drains vm+lgkm: tile0 + btl/gbuf ready

  for (int jt = 0; jt < 16; ++jt) {
    const int cur = jt & 1;
    const int j0 = jt * 64;
    if (jt < 15) stage(cur ^ 1, jt + 1);   // prefetch next tile (drains at loop tail)

    f32x4 sacc[4] = {};
    #pragma unroll
    for (int c = 0; c < 2; ++c) {
      #pragma unroll
      for (int nt = 0; nt < 4; ++nt) {
        short8 bk8 = *(const short8*)&Ks[cur][nt * 1024 + (c * 4 + quad) * 128 + l16 * 8];
        sacc[nt] = __builtin_amdgcn_mfma_f32_16x16x32_bf16(aq[c], bk8, sacc[nt], 0, 0, 0);
      }
    }

    float sc[4][4], mt[4];
    #pragma unroll
    for (int r = 0; r < 4; ++r) {
      int i_loc = wave * 16 + quad * 4 + r;
      int i_glob = it0 + i_loc;
      float g = gbuf[i_loc];
      float mx = -1e30f;
      #pragma unroll
      for (int nt = 0; nt < 4; ++nt) {
        int j = j0 + nt * 16 + l16;
        float s = sacc[nt][r] + g * bf2f(btl[j - i_glob + 1023]);
        sc[nt][r] = s;
        mx = fmaxf(mx, s);
      }
      mt[r] = mx;
    }
    #pragma unroll
    for (int m = 1; m < 16; m <<= 1)
      #pragma unroll
      for (int r = 0; r < 4; ++r) mt[r] = fmaxf(mt[r], __shfl_xor(mt[r], m, 64));

    float alpha[4], ls[4];
    #pragma unroll
    for (int r = 0; r < 4; ++r) {
      float mnew = fmaxf(mrow[r], mt[r]);
      alpha[r] = __expf(mrow[r] - mnew);
      mrow[r] = mnew;
      float lsum = 0.f;
      #pragma unroll
      for (int nt = 0; nt < 4; ++nt) {
        float p = __expf(sc[nt][r] - mnew);
        sc[nt][r] = p;
        lsum += p;
      }
      ls[r] = lsum;
    }
    #pragma unroll
    for (int m = 1; m < 16; m <<= 1)
      #pragma unroll
      for (int r = 0; r < 4; ++r) ls[r] += __shfl_xor(ls[r], m, 64);
    #pragma unroll
    for (int r = 0; r < 4; ++r) lrow[r] = lrow[r] * alpha[r] + ls[r];

    // P -> bf16 A-frag repack via per-wave LDS (same-wave RAW, lgkmcnt only)
    #pragma unroll
    for (int nt = 0; nt < 4; ++nt)
      #pragma unroll
      for (int r = 0; r < 4; ++r)
        Ps[wave][(nt * 2 + (l16 >> 3)) * 128 + (quad * 4 + r) * 8 + (l16 & 7)] = f2bf(sc[nt][r]);

    #pragma unroll
    for (int dt = 0; dt < 4; ++dt)
      #pragma unroll
      for (int r = 0; r < 4; ++r) oacc[dt][r] *= alpha[r];

    #pragma unroll
    for (int c = 0; c < 2; ++c) {
      short8 ap = *(const short8*)&Ps[wave][(c * 4 + quad) * 128 + l16 * 8];
      #pragma unroll
      for (int dt = 0; dt < 4; ++dt) {
        short8 bv8 = *(const short8*)&Vs[cur][dt * 1024 + (c * 4 + quad) * 128 + l16 * 8];
        oacc[dt] = __builtin_amdgcn_mfma_f32_16x16x32_bf16(ap, bv8, oacc[dt], 0, 0, 0);
      }
    }

    VMCNT(0);                          // next tile's gld_lds landed
    __builtin_amdgcn_s_barrier();      // all waves done reading cur
  }

  #pragma unroll
  for (int dt = 0; dt < 4; ++dt)
    #pragma unroll
    for (int r = 0; r < 4; ++r) {
      int i_loc = wave * 16 + quad * 4 + r;
      int d = dt * 16 + l16;
      float o = oacc[dt][r] / lrow[r];
      ctxb[((size_t)(b * 1024 + it0 + i_loc)) * 1024 + h * 64 + d] = f2bf(o);
    }
}

// ---------- fused reduce(+resid+bias) + LayerNorm (NP partials) ----------
template <bool WRITE_BF16, bool TWO_BIAS, int NP>
__global__ __launch_bounds__(256) void redln_kernel(
    const float* __restrict__ p0, const float* __restrict__ p1,
    const float* __restrict__ p2, const float* __restrict__ p3,
    const float* __restrict__ extra, const float* __restrict__ bias,
    const float* __restrict__ bias2,
    const float* __restrict__ g, const float* __restrict__ bta,
    float* __restrict__ outf, u16* __restrict__ outb) {
  __shared__ float red[8];
  int row = blockIdx.x, tid = threadIdx.x;
  int lane = tid & 63, wave = tid >> 6;
  size_t base = (size_t)row * 1024 + tid * 4;
  float4 a = *(const float4*)&p0[base];
  float4 bb = *(const float4*)&p1[base];
  float4 c = *(const float4*)&extra[base];
  float4 d = *(const float4*)&bias[tid * 4];
  float4 v;
  v.x = a.x + bb.x + c.x + d.x;
  v.y = a.y + bb.y + c.y + d.y;
  v.z = a.z + bb.z + c.z + d.z;
  v.w = a.w + bb.w + c.w + d.w;
  if (NP == 4) {
    float4 e2 = *(const float4*)&p2[base];
    float4 e3 = *(const float4*)&p3[base];
    v.x += e2.x + e3.x; v.y += e2.y + e3.y;
    v.z += e2.z + e3.z; v.w += e2.w + e3.w;
  }
  if (TWO_BIAS) {
    float4 d2 = *(const float4*)&bias2[tid * 4];
    v.x += d2.x; v.y += d2.y; v.z += d2.z; v.w += d2.w;
  }
  float s = v.x + v.y + v.z + v.w;
  #pragma unroll
  for (int m = 1; m < 64; m <<= 1) s += __shfl_xor(s, m, 64);
  if (lane == 0) red[wave] = s;
  __syncthreads();
  float mean = (red[0] + red[1] + red[2] + red[3]) * (1.f / 1024.f);
  float d0 = v.x - mean, d1 = v.y - mean, d2 = v.z - mean, d3 = v.w - mean;
  float sq = d0 * d0 + d1 * d1 + d2 * d2 + d3 * d3;
  #pragma unroll
  for (int m = 1; m < 64; m <<= 1) sq += __shfl_xor(sq, m, 64);
  if (lane == 0) red[4 + wave] = sq;
  __syncthreads();
  float var = (red[4] + red[5] + red[6] + red[7]) * (1.f / 1024.f);
  float rstd = rsqrtf(var + 1e-5f);
  float dd[4] = {d0, d1, d2, d3};
  #pragma unroll
  for (int e = 0; e < 4; ++e) {
    int cidx = tid * 4 + e;
    float val = dd[e] * rstd * g[cidx] + bta[cidx];
    outf[(size_t)row * 1024 + cidx] = val;
    if (WRITE_BF16) outb[(size_t)row * 1024 + cidx] = f2bf(val);
  }
}

// ---------- launch ----------
extern "C" void kernel_launch(void* const* d_in, const int* in_sizes, int n_in,
                              void* d_out, int out_size, void* d_ws, size_t ws_size,
                              hipStream_t stream) {
  const float* x    = (const float*)d_in[0];
  const float* Wq   = (const float*)d_in[1];  const float* bq  = (const float*)d_in[2];
  const float* Wk   = (const float*)d_in[3];  const float* bk  = (const float*)d_in[4];
  const float* Wv   = (const float*)d_in[5];  const float* bv  = (const float*)d_in[6];
  const float* Wo   = (const float*)d_in[7];  const float* bo  = (const float*)d_in[8];
  const float* Wg   = (const float*)d_in[9];  const float* bg  = (const float*)d_in[10];
  const float* gc   = (const float*)d_in[11];
  const float* rel  = (const float*)d_in[12];
  const float* ln1g = (const float*)d_in[13]; const float* ln1b = (const float*)d_in[14];
  const float* W1   = (const float*)d_in[15]; const float* b1  = (const float*)d_in[16];
  const float* W2   = (const float*)d_in[17]; const float* b2  = (const float*)d_in[18];
  const float* ln2g = (const float*)d_in[19]; const float* ln2b = (const float*)d_in[20];
  const float* Wad  = (const float*)d_in[21]; const float* bad = (const float*)d_in[22];
  const float* Wau  = (const float*)d_in[23]; const float* bau = (const float*)d_in[24];
  float* out = (float*)d_out;

  char* ws = (char*)d_ws;
  const size_t MB = 1ull << 20;
  const size_t KB = 1ull << 10;
  (void)n_in; (void)in_sizes; (void)out_size;

  const bool big = ws_size >= (135ull << 20);

  u16 *xb, *wqkv, *qb, *kb, *vbp, *vtb, *ctxb, *wob, *w1ad, *w2au, *ffadp, *hb;
  float *gate, *btab, *P0, *P1, *P2, *P3, *hf;
  xb    = (u16*)(ws + 0 * MB);
  wqkv  = (u16*)(ws + 8 * MB);
  ffadp = (u16*)(ws + 0 * MB);
  P0    = (float*)(ws + 34 * MB);
  P1    = (float*)(ws + 50 * MB);
  // Wo split-4 partials kz=2,3 -> ws 0..32MB (xb/wqkv dead by Wo)
  float* PW2 = (float*)(ws + 0 * MB);
  float* PW3 = (float*)(ws + 16 * MB);
  if (big) {
    P2   = (float*)(ws + 66 * MB);
    P3   = (float*)(ws + 82 * MB);
    qb   = (u16*)(ws + 66 * MB);
    kb   = (u16*)(ws + 74 * MB);
    vbp  = (u16*)(ws + 82 * MB);
    vtb  = (u16*)(ws + 90 * MB);
    hb   = (u16*)(ws + 82 * MB);      // after redln1 (vbp dead); dead before FF2 writes P3
    ctxb = (u16*)(ws + 98 * MB);
    hf   = (float*)(ws + 98 * MB);    // after redln1 (ctxb dead)
    wob  = (u16*)(ws + 114 * MB);
    w1ad = (u16*)(ws + 116 * MB);
    w2au = (u16*)(ws + 125 * MB);
    gate = (float*)(ws + 133 * MB + 512 * KB);
    btab = (float*)(ws + 133 * MB + 768 * KB);
  } else {
    qb   = (u16*)(ws + 14 * MB);
    kb   = (u16*)(ws + 22 * MB);
    vbp  = (u16*)(ws + 30 * MB);
    vtb  = (u16*)(ws + 38 * MB);
    gate = (float*)(ws + 46 * MB);
    btab = (float*)(ws + 46 * MB + 256 * KB);
    ctxb = (u16*)(ws + 66 * MB);
    wob  = (u16*)(ws + 74 * MB);
    w1ad = (u16*)(ws + 76 * MB);
    w2au = (u16*)(ws + 85 * MB);
    hf   = (float*)(ws + 94 * MB);
    hb   = (u16*)(ws + 110 * MB);
    P2   = (float*)(ws + 66 * MB);    // over ctxb (dead at FF2 time)
    P3   = (float*)(ws + 14 * MB);    // over qb/kb (dead at FF2 time)
  }

  auto cvt = [&](const float* src, u16* dst, int n) {
    cvt_bf16<<<(n / 4 + 255) / 256, 256, 0, stream>>>(src, dst, n / 4);
  };
  cvt(x, xb, 4096 * 1024);
  cvt(Wq, wqkv,               1024 * 1024);
  cvt(Wk, wqkv + 1024 * 1024, 1024 * 1024);
  cvt(Wv, wqkv + 2 * 1024 * 1024, 1024 * 1024);
  cvt(Wo, wob, 1024 * 1024);
  cvt(W1, w1ad, 4096 * 1024);
  cvt(Wad, w1ad + 4096 * 1024, 256 * 1024);
  cvt_pad<<<(1024 * 1024 + 255) / 256, 256, 0, stream>>>(W2, w2au, 1024, 4352, 1024 * 1024);
  cvt_pad<<<(64 * 1024 + 255) / 256, 256, 0, stream>>>(Wau, w2au + 4096, 64, 4352, 64 * 1024);

  btab_kernel<<<128, 256, 0, stream>>>(rel, btab);
  gate_kernel<<<16384, 256, 0, stream>>>(x, Wg, bg, gc, gate);

  // QKV: M=4096 N=3072 K=1024 (192 blocks, 32 K-tiles of 32)
  gemm256<0><<<dim3(16, 12, 1), 512, 0, stream>>>(xb, wqkv, 1024, 1024, 32, 32, 1,
      bq, bk, bv, nullptr, nullptr, nullptr, 0, qb, kb, vbp);
  vtrans_kernel<<<dim3(16, 64), 256, 0, stream>>>(vbp, vtb);
  // attention: grid (bh, it0-tiles) for XCD K/V locality
  attn_kernel<<<dim3(64, 16), 256, 0, stream>>>(qb, kb, vtb, gate, btab, ctxb);
  // Wo: M=4096 N=1024 K=1024, split-K x4 (256 blocks, 8 K-tiles each)
  gemm256<3><<<dim3(16, 4, 4), 512, 0, stream>>>(ctxb, wob, 1024, 1024, 8, 8, 4,
      nullptr, nullptr, nullptr, P0, PW2, PW3, 1024, nullptr, nullptr, nullptr);
  // reduce + bo + residual(x) + LN1 -> hf/hb
  redln_kernel<true, false, 4><<<4096, 256, 0, stream>>>(P0, P1, PW2, PW3, x, bo, nullptr,
      ln1g, ln1b, hf, hb);
  // FF1 + adapter-down fused: N=4352 = 17 x 256 (gelu cols<4096, elu cols>=4096)
  gemm256<2><<<dim3(16, 17, 1), 512, 0, stream>>>(hb, w1ad, 1024, 1024, 32, 32, 1,
      b1, bad, nullptr, nullptr, nullptr, nullptr, 0, ffadp, nullptr, nullptr);
  // FF2+adapter-up via K-concat: K=4352 = 136 K-tiles, split-K x4 (34 each)
  gemm256<3><<<dim3(16, 4, 4), 512, 0, stream>>>(ffadp, w2au, 4352, 4352, 34, 34, 4,
      nullptr, nullptr, nullptr, P0, P2, P3, 1024, nullptr, nullptr, nullptr);
  redln_kernel<false, true, 4><<<4096, 256, 0, stream>>>(P0, P1, P2, P3, hf, b2, bau,
      ln2g, ln2b, out, nullptr);
}

// Round 6
// 483.550 us; speedup vs baseline: 1.9532x; 1.9532x over previous
//
#include <hip/hip_runtime.h>
#include <cmath>

typedef unsigned short u16;
using short8 = __attribute__((ext_vector_type(8))) short;   // 8 x bf16
using f32x4  = __attribute__((ext_vector_type(4))) float;   // MFMA acc

// ---------- helpers ----------
__device__ __forceinline__ u16 f2bf(float f) {  // fp32 -> bf16 RNE
  union { float f; unsigned u; } c; c.f = f;
  unsigned r = c.u + 0x7fffu + ((c.u >> 16) & 1u);
  return (u16)(r >> 16);
}
__device__ __forceinline__ float bf2f(u16 b) {
  union { unsigned u; float f; } c; c.u = ((unsigned)b) << 16;
  return c.f;
}

__device__ __forceinline__ void gld_lds16(void* lds, const void* g) {
  __builtin_amdgcn_global_load_lds(
      (const __attribute__((address_space(1))) void*)g,
      (__attribute__((address_space(3))) void*)lds, 16, 0, 0);
}

// fast GELU (tanh approx, max err ~1e-3 << bf16 threshold)
__device__ __forceinline__ float gelu_fast(float t) {
  float u = 0.7978845608f * t * (1.f + 0.044715f * t * t);
  float th = 1.f - 2.f / (__expf(2.f * u) + 1.f);
  return 0.5f * t * (1.f + th);
}

// ---------- fp32 -> bf16 convert ----------
__global__ __launch_bounds__(256) void cvt_bf16(const float* __restrict__ in,
                                                u16* __restrict__ out, int n4) {
  int i = blockIdx.x * 256 + threadIdx.x;
  if (i >= n4) return;
  float4 v = ((const float4*)in)[i];
  ushort4 o;
  o.x = f2bf(v.x); o.y = f2bf(v.y); o.z = f2bf(v.z); o.w = f2bf(v.w);
  ((ushort4*)out)[i] = o;
}

// fp32 -> bf16 into strided (padded) rows
__global__ __launch_bounds__(256) void cvt_pad(const float* __restrict__ in,
                                               u16* __restrict__ out,
                                               int incols4, int outstride, int n4) {
  int i = blockIdx.x * 256 + threadIdx.x;
  if (i >= n4) return;
  int row = i / incols4, c = i - row * incols4;
  float4 v = ((const float4*)in)[i];
  ushort4 o;
  o.x = f2bf(v.x); o.y = f2bf(v.y); o.z = f2bf(v.z); o.w = f2bf(v.w);
  *(ushort4*)&out[(size_t)row * outstride + c * 4] = o;
}

// ---------- relative-position bias table ----------
__global__ __launch_bounds__(256) void btab_kernel(const float* __restrict__ rel_embed,
                                                   float* __restrict__ btab) {
  int idx = blockIdx.x * 256 + threadIdx.x;
  if (idx >= 16 * 2048) return;
  int h = idx >> 11;
  int d = idx & 2047;
  if (d >= 2047) return;
  int rel = d - 1023;
  int bucket = (rel > 0) ? 160 : 0;
  int ar = rel < 0 ? -rel : rel;
  if (ar < 80) {
    bucket += ar;
  } else {
    int large = 80 + (int)(logf((float)ar / 80.0f) / 2.3025851f * 80.0f);
    if (large > 159) large = 159;
    bucket += large;
  }
  btab[h * 2048 + d] = rel_embed[bucket * 16 + h];
}

// ---------- gate ----------
__global__ __launch_bounds__(256) void gate_kernel(const float* __restrict__ x,
                                                   const float* __restrict__ Wg,
                                                   const float* __restrict__ bg,
                                                   const float* __restrict__ gc,
                                                   float* __restrict__ gate_out) {
  int gw = blockIdx.x * 4 + (threadIdx.x >> 6);
  int lane = threadIdx.x & 63;
  int s = gw & 1023, bh = gw >> 10, b = bh >> 4, h = bh & 15;
  float wA = Wg[lane] + Wg[64 + lane] + Wg[128 + lane] + Wg[192 + lane];
  float wB = Wg[256 + lane] + Wg[320 + lane] + Wg[384 + lane] + Wg[448 + lane];
  float xv = x[((size_t)(b * 1024 + s)) * 1024 + h * 64 + lane];
  float pa = xv * wA, pb = xv * wB;
  #pragma unroll
  for (int m = 1; m < 64; m <<= 1) {
    pa += __shfl_xor(pa, m, 64);
    pb += __shfl_xor(pb, m, 64);
  }
  if (lane == 0) {
    float bgA = bg[0] + bg[1] + bg[2] + bg[3];
    float bgB = bg[4] + bg[5] + bg[6] + bg[7];
    float ga = 1.f / (1.f + expf(-(pa + bgA)));
    float gb = 1.f / (1.f + expf(-(pb + bgB)));
    gate_out[(size_t)bh * 1024 + s] = ga * (gb * gc[h] - 1.f) + 2.f;
  }
}

// ---------- V transpose: vt[bh][d][s] ----------
__global__ __launch_bounds__(256) void vtrans_kernel(const u16* __restrict__ vb,
                                                     u16* __restrict__ vt) {
  __shared__ u16 tile[64 * 65];
  int bh = blockIdx.y, b = bh >> 4, h = bh & 15;
  int s0 = blockIdx.x * 64;
  int tid = threadIdx.x;
  int r = tid >> 3, c = (tid & 7) * 8;
  #pragma unroll
  for (int p = 0; p < 2; ++p) {
    int s = p * 32 + r;
    uint4 vv = *(const uint4*)&vb[((size_t)(b * 1024 + s0 + s)) * 1024 + h * 64 + c];
    const u16* pv = (const u16*)&vv;
    #pragma unroll
    for (int e = 0; e < 8; ++e) tile[(c + e) * 65 + s] = pv[e];
  }
  __syncthreads();
  int d = tid & 63, jc0 = tid >> 6;
  #pragma unroll
  for (int jc = jc0; jc < 8; jc += 4) {
    u16 tmp[8];
    #pragma unroll
    for (int e = 0; e < 8; ++e) tmp[e] = tile[d * 65 + jc * 8 + e];
    *(uint4*)&vt[((size_t)(bh * 64 + d)) * 1024 + s0 + jc * 8] = *(uint4*)tmp;
  }
}

// ---------- GEMM 256x256, BK=32, 8 waves, 2-phase double-buffer ----------
// BK=32 -> LDS 64KB. __launch_bounds__(512,2): VGPR cap 256, compiler's
// natural 128 VGPR x 16 waves/CU = exactly the 512/SIMD pool, and 2x64KB LDS
// fits 160KB -> 2 blocks/CU BY RESOURCES (R5 lesson: launch_bounds(512,4)
// forced a 64-VGPR cap and spilled acc[8][4] to scratch: VGPR=64,
// WRITE_SIZE 34.8->473MB per dispatch, 2x regression. Never request an
// occupancy whose VGPR quota is below the live-state floor).
// 2 blocks/CU = 512 slots: 272/256/192-block grids fully co-resident (no
// R4 scheduling-round quantization) and the co-resident block's MFMA covers
// this block's stage+vmcnt(0) drain.
// Per K-tile: issue next-tile stage (4 x global_load_lds/thread) ->
// ds_read/MFMA current tile -> vmcnt(0) -> barrier. LDS chunk-XOR swizzle;
// staging pre-swizzles the per-lane GLOBAL address, LDS dest linear (rule 21);
// reads apply the same XOR (0 conflicts, verified R1-R5).
// MODE 0: QKV epilogue (seg bias + q*0.125, bf16 x3)
// MODE 2: FF1 gelu (cols<4096, bias0) / adapter elu (cols>=4096, bias1)
// MODE 3: fp32 partials (split-K x4), 4M-float stride, P0|P1 contiguous,
//         kz=2 -> outf2, kz=3 -> outf3
#define VMCNT(n) asm volatile("s_waitcnt vmcnt(" #n ")" ::: "memory")

#define G256_LDA(BUF, MH)                                                   \
  af_[0] = *(const short8*)&lds[BUF][0][aBase + (MH) * 2048 + 0];           \
  af_[1] = *(const short8*)&lds[BUF][0][aBase + (MH) * 2048 + 512];         \
  af_[2] = *(const short8*)&lds[BUF][0][aBase + (MH) * 2048 + 1024];        \
  af_[3] = *(const short8*)&lds[BUF][0][aBase + (MH) * 2048 + 1536];
#define G256_LDB(BUF)                                                       \
  bf_[0] = *(const short8*)&lds[BUF][1][bBase + 0];                         \
  bf_[1] = *(const short8*)&lds[BUF][1][bBase + 512];                       \
  bf_[2] = *(const short8*)&lds[BUF][1][bBase + 1024];                      \
  bf_[3] = *(const short8*)&lds[BUF][1][bBase + 1536];
#define G256_MFMA(MH)                                                       \
  _Pragma("unroll") for (int mi = 0; mi < 4; ++mi)                          \
  _Pragma("unroll") for (int ni = 0; ni < 4; ++ni)                          \
    acc[(MH) * 4 + mi][ni] = __builtin_amdgcn_mfma_f32_16x16x32_bf16(       \
        af_[mi], bf_[ni], acc[(MH) * 4 + mi][ni], 0, 0, 0);
#define G256_TILE(BUF)                                                      \
  G256_LDB(BUF)                                                             \
  G256_LDA(BUF, 0)                                                          \
  G256_MFMA(0)                                                              \
  G256_LDA(BUF, 1)                                                          \
  G256_MFMA(1)

template <int MODE>
__global__ __launch_bounds__(512, 2) void gemm256(
    const u16* __restrict__ A, const u16* __restrict__ Bw,
    int lda, int ldb, int kt_hi, int kt_lo, int z_hi,
    const float* __restrict__ bias0, const float* __restrict__ bias1,
    const float* __restrict__ bias2,
    float* __restrict__ outf, float* __restrict__ outf2,
    float* __restrict__ outf3, int ldo,
    u16* __restrict__ ob0, u16* __restrict__ ob1, u16* __restrict__ ob2) {
  __shared__ __align__(16) u16 lds[2][2][8192];   // [buf][A/B][256 rows x 32 cols]

  const int tid = threadIdx.x;
  const int lane = tid & 63, wave = tid >> 6;
  const int quad = lane >> 4, l16 = lane & 15;
  const int wm = wave >> 2, wn = wave & 3;

  // XCD-aware bijective swizzle (all grids are multiples of 8 blocks)
  const int gx = gridDim.x, gy = gridDim.y;
  int flat = blockIdx.x + gx * (blockIdx.y + gy * blockIdx.z);
  const int cpx = (gx * gy * gridDim.z) >> 3;
  flat = (flat & 7) * cpx + (flat >> 3);
  const int bmi = flat % gx;
  int rest = flat / gx;
  const int bni = rest % gy;
  const int kz = rest / gy;

  const int bm = bmi * 256, bn = bni * 256;
  const int nkt = (kz < z_hi) ? kt_hi : kt_lo;   // K-tiles of 32; must be EVEN
  const int ktb = (kz < z_hi) ? kz * kt_hi : z_hi * kt_hi + (kz - z_hi) * kt_lo;

  // staging geometry: lane l stages row (wave*16 + l/4) (+128 for 2nd load),
  // global 16B chunk (l&3)^((row>>1)&3) -> linear LDS dest.
  const int srow = wave * 16 + (lane >> 2);
  const int sk = (((lane & 3) ^ ((lane >> 3) & 3)) << 3);
  const u16* aG = A + (size_t)(bm + srow) * lda + (size_t)ktb * 32 + sk;
  const u16* bG = Bw + (size_t)(bn + srow) * ldb + (size_t)ktb * 32 + sk;
  const size_t aS = (size_t)128 * lda, bS = (size_t)128 * ldb;

  // frag read bases (u16 index inside one [8192] region)
  const int xsw = ((quad ^ ((l16 >> 1) & 3)) << 3);
  const int aBase = (wm * 128 + l16) * 32 + xsw;
  const int bBase = (wn * 64 + l16) * 32 + xsw;

  auto stA = [&](int buf, int kt) {
    const u16* g = aG + kt * 32;
    u16* d = (u16*)&lds[buf][0][wave * 512];
    gld_lds16(d, g);
    gld_lds16(d + 4096, g + aS);
  };
  auto stB = [&](int buf, int kt) {
    const u16* g = bG + kt * 32;
    u16* d = (u16*)&lds[buf][1][wave * 512];
    gld_lds16(d, g);
    gld_lds16(d + 4096, g + bS);
  };

  f32x4 acc[8][4] = {};
  short8 af_[4], bf_[4];

  // prologue: stage tile 0 -> buf0, drain, barrier
  stA(0, 0); stB(0, 0);
  VMCNT(0);
  __builtin_amdgcn_s_barrier();

  for (int J = 0; J < (nkt >> 1); ++J) {
    {  // even tile t=2J in buf0; prefetch t+1 -> buf1 (always exists)
      const int t1 = 2 * J + 1;
      stA(1, t1); stB(1, t1);
      G256_TILE(0)
      VMCNT(0);
      __builtin_amdgcn_s_barrier();
    }
    {  // odd tile t=2J+1 in buf1; prefetch t+2 -> buf0 (if exists)
      const int t2 = 2 * J + 2;
      if (t2 < nkt) { stA(0, t2); stB(0, t2); }
      G256_TILE(1)
      VMCNT(0);
      __builtin_amdgcn_s_barrier();
    }
  }

  const int m0 = bm + wm * 128 + quad * 4;
  const int n0 = bn + wn * 64 + l16;

  if constexpr (MODE == 0) {
    const int seg = bn >> 10;  // tile never straddles a 1024 segment
    const float* bs = seg == 0 ? bias0 : (seg == 1 ? bias1 : bias2);
    u16* dst = seg == 0 ? ob0 : (seg == 1 ? ob1 : ob2);
    const float sc = seg == 0 ? 0.125f : 1.0f;
    const int nb = (bn & 1023) + wn * 64 + l16;
    #pragma unroll
    for (int a = 0; a < 8; ++a)
      #pragma unroll
      for (int ni = 0; ni < 4; ++ni) {
        int nn = nb + ni * 16;
        float bv = bs[nn];
        #pragma unroll
        for (int r = 0; r < 4; ++r) {
          int m = m0 + a * 16 + r;
          dst[(size_t)m * 1024 + nn] = f2bf((acc[a][ni][r] + bv) * sc);
        }
      }
  } else if constexpr (MODE == 2) {
    const bool is_gelu = (bn < 4096);   // block-uniform
    #pragma unroll
    for (int a = 0; a < 8; ++a)
      #pragma unroll
      for (int ni = 0; ni < 4; ++ni) {
        int nn = n0 + ni * 16;
        float bv = is_gelu ? bias0[nn] : bias1[nn - 4096];
        #pragma unroll
        for (int r = 0; r < 4; ++r) {
          int m = m0 + a * 16 + r;
          float t = acc[a][ni][r] + bv;
          float res;
          if (is_gelu) res = gelu_fast(t);
          else         res = t > 0.f ? t : (__expf(t) - 1.f);
          ob0[(size_t)m * 4352 + nn] = f2bf(res);
        }
      }
  } else {  // MODE 3: fp32 partials
    float* op = (kz == 0) ? outf
              : (kz == 1) ? outf + 4194304
              : (kz == 2) ? outf2 : outf3;
    #pragma unroll
    for (int a = 0; a < 8; ++a)
      #pragma unroll
      for (int ni = 0; ni < 4; ++ni) {
        int nn = n0 + ni * 16;
        #pragma unroll
        for (int r = 0; r < 4; ++r)
          op[(size_t)(m0 + a * 16 + r) * ldo + nn] = acc[a][ni][r];
      }
  }
}

// ---------- flash attention: LDS-staged K/V, double-buffered (2-phase) ----------
// R4-verified structure: global_load_lds for tile jt+1 issued BEFORE compute
// of tile jt, drains at end-of-iteration vmcnt(0)+barrier. Grid (bh, it0):
// flat%8 = bh%8 -> one XCD per (b,h) (FETCH 70->13MB, R3-verified).
__global__ __launch_bounds__(256) void attn_kernel(
    const u16* __restrict__ qb, const u16* __restrict__ kb, const u16* __restrict__ vt,
    const float* __restrict__ gate, const float* __restrict__ btab,
    u16* __restrict__ ctxb) {
  __shared__ __align__(16) u16 Ks[2][64 * 64];
  __shared__ __align__(16) u16 Vs[2][64 * 64];
  __shared__ __align__(16) u16 Ps[4][16 * 64];
  __shared__ u16 btl[2048];
  __shared__ float gbuf[64];

  const int tid = threadIdx.x;
  const int lane = tid & 63, wave = tid >> 6;
  const int quad = lane >> 4, l16 = lane & 15;
  const int bh = blockIdx.x, b = bh >> 4, h = bh & 15;
  const int it0 = blockIdx.y * 64;
  const int sr = lane & 15;
  const int skc = (lane >> 4) * 8;

  // stage K/V tile jt into buffer buf (4 x global_load_lds per wave-slab)
  auto stage = [&](int buf, int jt) {
    const int j0 = jt * 64;
    #pragma unroll
    for (int hf = 0; hf < 2; ++hf) {
      gld_lds16(&Ks[buf][wave * 1024 + hf * 512],
                &kb[((size_t)(b * 1024 + j0 + wave * 16 + sr)) * 1024 + h * 64 + hf * 32 + skc]);
      gld_lds16(&Vs[buf][wave * 1024 + hf * 512],
                &vt[((size_t)(bh * 64 + wave * 16 + sr)) * 1024 + j0 + hf * 32 + skc]);
    }
  };

  for (int idx = tid; idx < 2047; idx += 256) btl[idx] = f2bf(btab[h * 2048 + idx]);
  if (tid < 64) gbuf[tid] = gate[(size_t)bh * 1024 + it0 + tid];

  // Q fragments held in registers for the whole kernel
  short8 aq[2];
  #pragma unroll
  for (int c = 0; c < 2; ++c)
    aq[c] = *(const short8*)&qb[((size_t)(b * 1024 + it0 + wave * 16 + l16)) * 1024 +
                                h * 64 + c * 32 + quad * 8];

  f32x4 oacc[4] = {};
  float mrow[4], lrow[4];
  #pragma unroll
  for (int r = 0; r < 4; ++r) { mrow[r] = -1e30f; lrow[r] = 0.f; }

  stage(0, 0);
  __syncthreads();   // drains vm+lgkm: tile0 + btl/gbuf ready

  for (int jt = 0; jt < 16; ++jt) {
    const int cur = jt & 1;
    const int j0 = jt * 64;
    if (jt < 15) stage(cur ^ 1, jt + 1);   // prefetch next tile (drains at loop tail)

    f32x4 sacc[4] = {};
    #pragma unroll
    for (int c = 0; c < 2; ++c) {
      #pragma unroll
      for (int nt = 0; nt < 4; ++nt) {
        short8 bk8 = *(const short8*)&Ks[cur][nt * 1024 + (c * 4 + quad) * 128 + l16 * 8];
        sacc[nt] = __builtin_amdgcn_mfma_f32_16x16x32_bf16(aq[c], bk8, sacc[nt], 0, 0, 0);
      }
    }

    float sc[4][4], mt[4];
    #pragma unroll
    for (int r = 0; r < 4; ++r) {
      int i_loc = wave * 16 + quad * 4 + r;
      int i_glob = it0 + i_loc;
      float g = gbuf[i_loc];
      float mx = -1e30f;
      #pragma unroll
      for (int nt = 0; nt < 4; ++nt) {
        int j = j0 + nt * 16 + l16;
        float s = sacc[nt][r] + g * bf2f(btl[j - i_glob + 1023]);
        sc[nt][r] = s;
        mx = fmaxf(mx, s);
      }
      mt[r] = mx;
    }
    #pragma unroll
    for (int m = 1; m < 16; m <<= 1)
      #pragma unroll
      for (int r = 0; r < 4; ++r) mt[r] = fmaxf(mt[r], __shfl_xor(mt[r], m, 64));

    float alpha[4], ls[4];
    #pragma unroll
    for (int r = 0; r < 4; ++r) {
      float mnew = fmaxf(mrow[r], mt[r]);
      alpha[r] = __expf(mrow[r] - mnew);
      mrow[r] = mnew;
      float lsum = 0.f;
      #pragma unroll
      for (int nt = 0; nt < 4; ++nt) {
        float p = __expf(sc[nt][r] - mnew);
        sc[nt][r] = p;
        lsum += p;
      }
      ls[r] = lsum;
    }
    #pragma unroll
    for (int m = 1; m < 16; m <<= 1)
      #pragma unroll
      for (int r = 0; r < 4; ++r) ls[r] += __shfl_xor(ls[r], m, 64);
    #pragma unroll
    for (int r = 0; r < 4; ++r) lrow[r] = lrow[r] * alpha[r] + ls[r];

    // P -> bf16 A-frag repack via per-wave LDS (same-wave RAW, lgkmcnt only)
    #pragma unroll
    for (int nt = 0; nt < 4; ++nt)
      #pragma unroll
      for (int r = 0; r < 4; ++r)
        Ps[wave][(nt * 2 + (l16 >> 3)) * 128 + (quad * 4 + r) * 8 + (l16 & 7)] = f2bf(sc[nt][r]);

    #pragma unroll
    for (int dt = 0; dt < 4; ++dt)
      #pragma unroll
      for (int r = 0; r < 4; ++r) oacc[dt][r] *= alpha[r];

    #pragma unroll
    for (int c = 0; c < 2; ++c) {
      short8 ap = *(const short8*)&Ps[wave][(c * 4 + quad) * 128 + l16 * 8];
      #pragma unroll
      for (int dt = 0; dt < 4; ++dt) {
        short8 bv8 = *(const short8*)&Vs[cur][dt * 1024 + (c * 4 + quad) * 128 + l16 * 8];
        oacc[dt] = __builtin_amdgcn_mfma_f32_16x16x32_bf16(ap, bv8, oacc[dt], 0, 0, 0);
      }
    }

    VMCNT(0);                          // next tile's gld_lds landed
    __builtin_amdgcn_s_barrier();      // all waves done reading cur
  }

  #pragma unroll
  for (int dt = 0; dt < 4; ++dt)
    #pragma unroll
    for (int r = 0; r < 4; ++r) {
      int i_loc = wave * 16 + quad * 4 + r;
      int d = dt * 16 + l16;
      float o = oacc[dt][r] / lrow[r];
      ctxb[((size_t)(b * 1024 + it0 + i_loc)) * 1024 + h * 64 + d] = f2bf(o);
    }
}

// ---------- fused reduce(+resid+bias) + LayerNorm (NP partials) ----------
template <bool WRITE_BF16, bool TWO_BIAS, int NP>
__global__ __launch_bounds__(256) void redln_kernel(
    const float* __restrict__ p0, const float* __restrict__ p1,
    const float* __restrict__ p2, const float* __restrict__ p3,
    const float* __restrict__ extra, const float* __restrict__ bias,
    const float* __restrict__ bias2,
    const float* __restrict__ g, const float* __restrict__ bta,
    float* __restrict__ outf, u16* __restrict__ outb) {
  __shared__ float red[8];
  int row = blockIdx.x, tid = threadIdx.x;
  int lane = tid & 63, wave = tid >> 6;
  size_t base = (size_t)row * 1024 + tid * 4;
  float4 a = *(const float4*)&p0[base];
  float4 bb = *(const float4*)&p1[base];
  float4 c = *(const float4*)&extra[base];
  float4 d = *(const float4*)&bias[tid * 4];
  float4 v;
  v.x = a.x + bb.x + c.x + d.x;
  v.y = a.y + bb.y + c.y + d.y;
  v.z = a.z + bb.z + c.z + d.z;
  v.w = a.w + bb.w + c.w + d.w;
  if (NP == 4) {
    float4 e2 = *(const float4*)&p2[base];
    float4 e3 = *(const float4*)&p3[base];
    v.x += e2.x + e3.x; v.y += e2.y + e3.y;
    v.z += e2.z + e3.z; v.w += e2.w + e3.w;
  }
  if (TWO_BIAS) {
    float4 d2 = *(const float4*)&bias2[tid * 4];
    v.x += d2.x; v.y += d2.y; v.z += d2.z; v.w += d2.w;
  }
  float s = v.x + v.y + v.z + v.w;
  #pragma unroll
  for (int m = 1; m < 64; m <<= 1) s += __shfl_xor(s, m, 64);
  if (lane == 0) red[wave] = s;
  __syncthreads();
  float mean = (red[0] + red[1] + red[2] + red[3]) * (1.f / 1024.f);
  float d0 = v.x - mean, d1 = v.y - mean, d2 = v.z - mean, d3 = v.w - mean;
  float sq = d0 * d0 + d1 * d1 + d2 * d2 + d3 * d3;
  #pragma unroll
  for (int m = 1; m < 64; m <<= 1) sq += __shfl_xor(sq, m, 64);
  if (lane == 0) red[4 + wave] = sq;
  __syncthreads();
  float var = (red[4] + red[5] + red[6] + red[7]) * (1.f / 1024.f);
  float rstd = rsqrtf(var + 1e-5f);
  float dd[4] = {d0, d1, d2, d3};
  #pragma unroll
  for (int e = 0; e < 4; ++e) {
    int cidx = tid * 4 + e;
    float val = dd[e] * rstd * g[cidx] + bta[cidx];
    outf[(size_t)row * 1024 + cidx] = val;
    if (WRITE_BF16) outb[(size_t)row * 1024 + cidx] = f2bf(val);
  }
}

// ---------- launch ----------
extern "C" void kernel_launch(void* const* d_in, const int* in_sizes, int n_in,
                              void* d_out, int out_size, void* d_ws, size_t ws_size,
                              hipStream_t stream) {
  const float* x    = (const float*)d_in[0];
  const float* Wq   = (const float*)d_in[1];  const float* bq  = (const float*)d_in[2];
  const float* Wk   = (const float*)d_in[3];  const float* bk  = (const float*)d_in[4];
  const float* Wv   = (const float*)d_in[5];  const float* bv  = (const float*)d_in[6];
  const float* Wo   = (const float*)d_in[7];  const float* bo  = (const float*)d_in[8];
  const float* Wg   = (const float*)d_in[9];  const float* bg  = (const float*)d_in[10];
  const float* gc   = (const float*)d_in[11];
  const float* rel  = (const float*)d_in[12];
  const float* ln1g = (const float*)d_in[13]; const float* ln1b = (const float*)d_in[14];
  const float* W1   = (const float*)d_in[15]; const float* b1  = (const float*)d_in[16];
  const float* W2   = (const float*)d_in[17]; const float* b2  = (const float*)d_in[18];
  const float* ln2g = (const float*)d_in[19]; const float* ln2b = (const float*)d_in[20];
  const float* Wad  = (const float*)d_in[21]; const float* bad = (const float*)d_in[22];
  const float* Wau  = (const float*)d_in[23]; const float* bau = (const float*)d_in[24];
  float* out = (float*)d_out;

  char* ws = (char*)d_ws;
  const size_t MB = 1ull << 20;
  const size_t KB = 1ull << 10;
  (void)n_in; (void)in_sizes; (void)out_size;

  const bool big = ws_size >= (135ull << 20);

  u16 *xb, *wqkv, *qb, *kb, *vbp, *vtb, *ctxb, *wob, *w1ad, *w2au, *ffadp, *hb;
  float *gate, *btab, *P0, *P1, *P2, *P3, *hf;
  xb    = (u16*)(ws + 0 * MB);
  wqkv  = (u16*)(ws + 8 * MB);
  ffadp = (u16*)(ws + 0 * MB);
  P0    = (float*)(ws + 34 * MB);
  P1    = (float*)(ws + 50 * MB);
  // Wo split-4 partials kz=2,3 -> ws 0..32MB (xb/wqkv dead by Wo)
  float* PW2 = (float*)(ws + 0 * MB);
  float* PW3 = (float*)(ws + 16 * MB);
  if (big) {
    P2   = (float*)(ws + 66 * MB);
    P3   = (float*)(ws + 82 * MB);
    qb   = (u16*)(ws + 66 * MB);
    kb   = (u16*)(ws + 74 * MB);
    vbp  = (u16*)(ws + 82 * MB);
    vtb  = (u16*)(ws + 90 * MB);
    hb   = (u16*)(ws + 82 * MB);      // after redln1 (vbp dead); dead before FF2 writes P3
    ctxb = (u16*)(ws + 98 * MB);
    hf   = (float*)(ws + 98 * MB);    // after redln1 (ctxb dead)
    wob  = (u16*)(ws + 114 * MB);
    w1ad = (u16*)(ws + 116 * MB);
    w2au = (u16*)(ws + 125 * MB);
    gate = (float*)(ws + 133 * MB + 512 * KB);
    btab = (float*)(ws + 133 * MB + 768 * KB);
  } else {
    qb   = (u16*)(ws + 14 * MB);
    kb   = (u16*)(ws + 22 * MB);
    vbp  = (u16*)(ws + 30 * MB);
    vtb  = (u16*)(ws + 38 * MB);
    gate = (float*)(ws + 46 * MB);
    btab = (float*)(ws + 46 * MB + 256 * KB);
    ctxb = (u16*)(ws + 66 * MB);
    wob  = (u16*)(ws + 74 * MB);
    w1ad = (u16*)(ws + 76 * MB);
    w2au = (u16*)(ws + 85 * MB);
    hf   = (float*)(ws + 94 * MB);
    hb   = (u16*)(ws + 110 * MB);
    P2   = (float*)(ws + 66 * MB);    // over ctxb (dead at FF2 time)
    P3   = (float*)(ws + 14 * MB);    // over qb/kb (dead at FF2 time)
  }

  auto cvt = [&](const float* src, u16* dst, int n) {
    cvt_bf16<<<(n / 4 + 255) / 256, 256, 0, stream>>>(src, dst, n / 4);
  };
  cvt(x, xb, 4096 * 1024);
  cvt(Wq, wqkv,               1024 * 1024);
  cvt(Wk, wqkv + 1024 * 1024, 1024 * 1024);
  cvt(Wv, wqkv + 2 * 1024 * 1024, 1024 * 1024);
  cvt(Wo, wob, 1024 * 1024);
  cvt(W1, w1ad, 4096 * 1024);
  cvt(Wad, w1ad + 4096 * 1024, 256 * 1024);
  cvt_pad<<<(1024 * 1024 + 255) / 256, 256, 0, stream>>>(W2, w2au, 1024, 4352, 1024 * 1024);
  cvt_pad<<<(64 * 1024 + 255) / 256, 256, 0, stream>>>(Wau, w2au + 4096, 64, 4352, 64 * 1024);

  btab_kernel<<<128, 256, 0, stream>>>(rel, btab);
  gate_kernel<<<16384, 256, 0, stream>>>(x, Wg, bg, gc, gate);

  // QKV: M=4096 N=3072 K=1024 (192 blocks, 32 K-tiles of 32)
  gemm256<0><<<dim3(16, 12, 1), 512, 0, stream>>>(xb, wqkv, 1024, 1024, 32, 32, 1,
      bq, bk, bv, nullptr, nullptr, nullptr, 0, qb, kb, vbp);
  vtrans_kernel<<<dim3(16, 64), 256, 0, stream>>>(vbp, vtb);
  // attention: grid (bh, it0-tiles) for XCD K/V locality
  attn_kernel<<<dim3(64, 16), 256, 0, stream>>>(qb, kb, vtb, gate, btab, ctxb);
  // Wo: M=4096 N=1024 K=1024, split-K x4 (256 blocks, 8 K-tiles each)
  gemm256<3><<<dim3(16, 4, 4), 512, 0, stream>>>(ctxb, wob, 1024, 1024, 8, 8, 4,
      nullptr, nullptr, nullptr, P0, PW2, PW3, 1024, nullptr, nullptr, nullptr);
  // reduce + bo + residual(x) + LN1 -> hf/hb
  redln_kernel<true, false, 4><<<4096, 256, 0, stream>>>(P0, P1, PW2, PW3, x, bo, nullptr,
      ln1g, ln1b, hf, hb);
  // FF1 + adapter-down fused: N=4352 = 17 x 256 (gelu cols<4096, elu cols>=4096)
  gemm256<2><<<dim3(16, 17, 1), 512, 0, stream>>>(hb, w1ad, 1024, 1024, 32, 32, 1,
      b1, bad, nullptr, nullptr, nullptr, nullptr, 0, ffadp, nullptr, nullptr);
  // FF2+adapter-up via K-concat: K=4352 = 136 K-tiles, split-K x4 (34 each)
  gemm256<3><<<dim3(16, 4, 4), 512, 0, stream>>>(ffadp, w2au, 4352, 4352, 34, 34, 4,
      nullptr, nullptr, nullptr, P0, P2, P3, 1024, nullptr, nullptr, nullptr);
  redln_kernel<false, true, 4><<<4096, 256, 0, stream>>>(P0, P1, P2, P3, hf, b2, bau,
      ln2g, ln2b, out, nullptr);
}